// Round 10
// baseline (68.487 us; speedup 1.0000x reference)
//
#include <hip/hip_runtime.h>
#include <hip/hip_bf16.h>

typedef unsigned short u16;
typedef __attribute__((ext_vector_type(8))) __bf16 bf16x8;
typedef __attribute__((ext_vector_type(4))) float f32x4;

#define B_ 4
#define T_ 2048
#define C_ 1024
#define H_ 64
#define NSEG 8

__device__ __forceinline__ u16 f2bf(float f) {
    union { __hip_bfloat16 h; u16 u; } cv;
    cv.h = __float2bfloat16(f);
    return cv.u;
}

__device__ __forceinline__ float bf2f(unsigned v) {
    union { unsigned u; float f; } c; c.u = v << 16; return c.f;
}

__device__ __forceinline__ bf16x8 cvt8r(float4 f0, float4 f1) {
    union { u16 h[8]; bf16x8 v; } ua;
    ua.h[0] = f2bf(f0.x); ua.h[1] = f2bf(f0.y);
    ua.h[2] = f2bf(f0.z); ua.h[3] = f2bf(f0.w);
    ua.h[4] = f2bf(f1.x); ua.h[5] = f2bf(f1.y);
    ua.h[6] = f2bf(f1.z); ua.h[7] = f2bf(f1.w);
    return ua.v;
}

// ---------------- Kernel 0: W fp32 -> bf16 (once) ----------------
__global__ __launch_bounds__(256) void wcvt(
    const float* __restrict__ wq, const float* __restrict__ wk,
    const float* __restrict__ wv, u16* __restrict__ wcat)
{
    int e = (blockIdx.x * 256 + threadIdx.x) * 4;
    int row = e >> 10, col = e & 1023;
    const float* src = (row < 64) ? (wq + (size_t)row * C_)
                     : (row < 128) ? (wk + (size_t)(row - 64) * C_)
                                   : (wv + (size_t)(row - 128) * C_);
    float4 f = *(const float4*)(src + col);
    u16 o[4] = { f2bf(f.x), f2bf(f.y), f2bf(f.z), f2bf(f.w) };
    *(uint2*)(wcat + e) = *(uint2*)o;
}

// ---------------- Kernel 1: QKV projection ----------------
// Block = 16-row M-tile, 4 waves = K-split x4 (wave ks owns K [ks*256,(ks+1)*256)).
// 512 blocks x 256 thr, 25 KB LDS, no VGPR cap -> multi-block residency per CU.
__global__ __launch_bounds__(256, 2) void qkv(
    const float* __restrict__ x, const u16* __restrict__ wcat,
    u16* __restrict__ q, u16* __restrict__ k, u16* __restrict__ vT)
{
    __shared__ float red[2][16][196];   // 25.1 KB; 2-way worst bank alias (free)

    const int tid  = threadIdx.x;
    const int lane = tid & 63;
    const int ks   = tid >> 6;          // 0..3 = K-slice
    const int m0   = blockIdx.x * 16;

    const int lr = lane & 15;
    const int g  = lane >> 4;

    const size_t kbase = (size_t)ks * 256 + g * 8;
    const float* xr = x + (size_t)(m0 + lr) * C_ + kbase;
    const u16*   wb = wcat + (size_t)lr * C_ + kbase;

    f32x4 acc[12] = {};

    #pragma unroll
    for (int kstep = 0; kstep < 8; ++kstep) {
        float4 f0 = *(const float4*)(xr + kstep * 32);
        float4 f1 = *(const float4*)(xr + kstep * 32 + 4);
        bf16x8 a = cvt8r(f0, f1);
        #pragma unroll
        for (int j = 0; j < 12; ++j) {
            bf16x8 b = *(const bf16x8*)(wb + (size_t)j * 16 * C_ + kstep * 32);
            acc[j] = __builtin_amdgcn_mfma_f32_16x16x32_bf16(a, b, acc[j], 0, 0, 0);
        }
    }

    // tree reduction 4 -> 2 -> 1
    if (ks >= 2)
        #pragma unroll
        for (int j = 0; j < 12; ++j)
            #pragma unroll
            for (int i = 0; i < 4; ++i)
                red[ks - 2][g * 4 + i][j * 16 + lr] = acc[j][i];
    __syncthreads();
    if (ks < 2)
        #pragma unroll
        for (int j = 0; j < 12; ++j)
            #pragma unroll
            for (int i = 0; i < 4; ++i)
                acc[j][i] += red[ks][g * 4 + i][j * 16 + lr];
    __syncthreads();
    if (ks == 1)
        #pragma unroll
        for (int j = 0; j < 12; ++j)
            #pragma unroll
            for (int i = 0; i < 4; ++i)
                red[0][g * 4 + i][j * 16 + lr] = acc[j][i];
    __syncthreads();
    if (ks != 0) return;

    // epilogue (wave 0): C/D layout col=lane&15, row=(lane>>4)*4+i
    #pragma unroll
    for (int j = 0; j < 12; ++j) {
        int n = j * 16 + lr;
        #pragma unroll
        for (int i = 0; i < 4; ++i) {
            float sum = acc[j][i] + red[0][g * 4 + i][j * 16 + lr];
            int m = m0 + g * 4 + i;
            u16 val = f2bf(sum);
            if (n < 64) {
                q[(size_t)m * H_ + n] = val;
            } else if (n < 128) {
                k[(size_t)m * H_ + (n - 64)] = val;
            } else {
                int b = m >> 11, t = m & 2047;
                vT[((size_t)b * H_ + (n - 128)) * T_ + t] = val;
            }
        }
    }
}

// ---------------- Kernel 2: causal flash attention, KV-split x8 ----------
// 1-wave blocks: no barriers (intra-wave LDS ordering via lgkmcnt); V hoisted.
__global__ __launch_bounds__(64) void attn_part(
    const u16* __restrict__ q, const u16* __restrict__ k,
    const u16* __restrict__ vT, u16* __restrict__ opart,
    float* __restrict__ ml)
{
    __shared__ u16 ps[16 * 72];

    const int lane = threadIdx.x;
    const int bid  = blockIdx.x;
    const int seg  = bid & (NSEG - 1);
    const int tix  = bid >> 3;
    const int b    = tix & 3;
    const int qt   = 127 - (tix >> 2);
    const int q0   = qt * 16;
    const size_t bT = (size_t)b * T_;

    const int lr = lane & 15;
    const int g  = lane >> 4;
    const int lk = g * 8;

    const int nch = (qt >> 2) + 1;
    const int L   = (nch + NSEG - 1) >> 3;
    const int c0  = seg * L;
    const int c1  = min(nch, c0 + L);

    if (c0 >= c1) {
        if (lr == 0)
            #pragma unroll
            for (int i = 0; i < 4; ++i) {
                ml[(size_t)bid * 32 + (g * 4 + i) * 2]     = -1e30f;
                ml[(size_t)bid * 32 + (g * 4 + i) * 2 + 1] = 0.f;
            }
        return;
    }

    bf16x8 aq[2];
    #pragma unroll
    for (int ks = 0; ks < 2; ++ks)
        aq[ks] = *(const bf16x8*)(q + (bT + q0 + lr) * H_ + ks * 32 + lk);

    f32x4 oacc[4] = {};
    float mrow[4], lrow[4];
    #pragma unroll
    for (int i = 0; i < 4; ++i) { mrow[i] = -1e30f; lrow[i] = 0.f; }

    for (int jc = c0; jc < c1; ++jc) {
        const int kv0 = jc << 6;

        bf16x8 bk[8];
        #pragma unroll
        for (int jf = 0; jf < 4; ++jf)
            #pragma unroll
            for (int ks = 0; ks < 2; ++ks)
                bk[jf * 2 + ks] = *(const bf16x8*)(k + (bT + kv0 + jf * 16 + lr) * H_ + ks * 32 + lk);

        f32x4 sacc[4] = {};
        #pragma unroll
        for (int jf = 0; jf < 4; ++jf)
            #pragma unroll
            for (int ks = 0; ks < 2; ++ks)
                sacc[jf] = __builtin_amdgcn_mfma_f32_16x16x32_bf16(aq[ks], bk[jf * 2 + ks], sacc[jf], 0, 0, 0);

        // V fragments issued BEFORE softmax: latency hides under exp/shuffles
        bf16x8 bv[8];
        #pragma unroll
        for (int jf = 0; jf < 4; ++jf)
            #pragma unroll
            for (int ks = 0; ks < 2; ++ks)
                bv[jf * 2 + ks] = *(const bf16x8*)(vT + ((size_t)b * H_ + jf * 16 + lr) * T_ + kv0 + ks * 32 + lk);

        const bool full = (kv0 + 63 <= q0);
        #pragma unroll
        for (int jf = 0; jf < 4; ++jf) {
            int col = kv0 + jf * 16 + lr;
            #pragma unroll
            for (int i = 0; i < 4; ++i) {
                int row = q0 + g * 4 + i;
                float val = sacc[jf][i] * 0.03125f;
                sacc[jf][i] = (full || col <= row) ? val : -1e30f;
            }
        }

        float pnew[4][4];
        #pragma unroll
        for (int i = 0; i < 4; ++i) {
            float mx = fmaxf(fmaxf(sacc[0][i], sacc[1][i]), fmaxf(sacc[2][i], sacc[3][i]));
            mx = fmaxf(mx, __shfl_xor(mx, 1));
            mx = fmaxf(mx, __shfl_xor(mx, 2));
            mx = fmaxf(mx, __shfl_xor(mx, 4));
            mx = fmaxf(mx, __shfl_xor(mx, 8));
            float mnew = fmaxf(mrow[i], mx);
            float corr = __expf(mrow[i] - mnew);
            float rs = 0.f;
            #pragma unroll
            for (int jf = 0; jf < 4; ++jf) {
                float p = __expf(sacc[jf][i] - mnew);
                pnew[jf][i] = p;
                rs += p;
            }
            rs += __shfl_xor(rs, 1);
            rs += __shfl_xor(rs, 2);
            rs += __shfl_xor(rs, 4);
            rs += __shfl_xor(rs, 8);
            lrow[i] = lrow[i] * corr + rs;
            mrow[i] = mnew;
            #pragma unroll
            for (int jf = 0; jf < 4; ++jf) oacc[jf][i] *= corr;
        }

        // P -> LDS (C/D -> A layout) -- single wave, no barrier needed
        #pragma unroll
        for (int jf = 0; jf < 4; ++jf)
            #pragma unroll
            for (int i = 0; i < 4; ++i)
                ps[(g * 4 + i) * 72 + jf * 16 + lr] = f2bf(pnew[jf][i]);

        #pragma unroll
        for (int ks2 = 0; ks2 < 2; ++ks2) {
            bf16x8 ap = *(const bf16x8*)(ps + lr * 72 + ks2 * 32 + lk);
            #pragma unroll
            for (int jf = 0; jf < 4; ++jf)
                oacc[jf] = __builtin_amdgcn_mfma_f32_16x16x32_bf16(ap, bv[jf * 2 + ks2], oacc[jf], 0, 0, 0);
        }
    }

    #pragma unroll
    for (int jf = 0; jf < 4; ++jf)
        #pragma unroll
        for (int i = 0; i < 4; ++i)
            opart[(size_t)bid * 1024 + (g * 4 + i) * 64 + jf * 16 + lr] = f2bf(oacc[jf][i]);
    if (lr == 0)
        #pragma unroll
        for (int i = 0; i < 4; ++i) {
            ml[(size_t)bid * 32 + (g * 4 + i) * 2]     = mrow[i];
            ml[(size_t)bid * 32 + (g * 4 + i) * 2 + 1] = lrow[i];
        }
}

// ---------------- Kernel 3: merge segments (bf16 partials) ----------------
__global__ __launch_bounds__(256) void attn_reduce(
    const u16* __restrict__ opart, const float* __restrict__ ml,
    float* __restrict__ out)
{
    const int t   = blockIdx.x;
    const int row = threadIdx.x >> 4;
    const int p   = threadIdx.x & 15;
    const int b   = t & 3;
    const int qt  = 127 - (t >> 2);

    float m[NSEG], l[NSEG];
    #pragma unroll
    for (int s = 0; s < NSEG; ++s) {
        m[s] = ml[(size_t)(t * NSEG + s) * 32 + row * 2];
        l[s] = ml[(size_t)(t * NSEG + s) * 32 + row * 2 + 1];
    }
    float M = m[0];
    #pragma unroll
    for (int s = 1; s < NSEG; ++s) M = fmaxf(M, m[s]);

    float a0 = 0.f, a1 = 0.f, a2 = 0.f, a3 = 0.f, Lsum = 0.f;
    #pragma unroll
    for (int s = 0; s < NSEG; ++s) {
        float wgt = __expf(m[s] - M);
        Lsum += l[s] * wgt;
        uint2 o = *(const uint2*)(opart + (size_t)(t * NSEG + s) * 1024 + row * 64 + p * 4);
        a0 += wgt * bf2f(o.x & 0xffffu);
        a1 += wgt * bf2f(o.x >> 16);
        a2 += wgt * bf2f(o.y & 0xffffu);
        a3 += wgt * bf2f(o.y >> 16);
    }
    float inv = 1.f / Lsum;
    float4 r; r.x = a0 * inv; r.y = a1 * inv; r.z = a2 * inv; r.w = a3 * inv;
    *(float4*)(out + ((size_t)b * T_ + qt * 16 + row) * H_ + p * 4) = r;
}

extern "C" void kernel_launch(void* const* d_in, const int* in_sizes, int n_in,
                              void* d_out, int out_size, void* d_ws, size_t ws_size,
                              hipStream_t stream) {
    const float* x  = (const float*)d_in[0];
    const float* wq = (const float*)d_in[1];
    const float* wk = (const float*)d_in[2];
    const float* wv = (const float*)d_in[3];

    u16* qws  = (u16*)d_ws;                          // 1 MB
    u16* kws  = qws + (size_t)B_ * T_ * H_;          // 1 MB
    u16* vTws = kws + (size_t)B_ * T_ * H_;          // 1 MB
    u16* wcat = vTws + (size_t)B_ * T_ * H_;         // 384 KB
    u16* opart = wcat + (size_t)192 * C_;            // 4096*1024 u16 = 8.4 MB
    float* mlbuf = (float*)(opart + (size_t)4096 * 1024);  // 512 KB

    wcvt<<<192, 256, 0, stream>>>(wq, wk, wv, wcat);
    qkv<<<512, 256, 0, stream>>>(x, wcat, qws, kws, vTws);
    attn_part<<<4096, 64, 0, stream>>>(qws, kws, vTws, opart, mlbuf);
    attn_reduce<<<512, 256, 0, stream>>>(opart, mlbuf, (float*)d_out);
}

// Round 11
// 66.373 us; speedup vs baseline: 1.0319x; 1.0319x over previous
//
#include <hip/hip_runtime.h>
#include <hip/hip_bf16.h>

typedef unsigned short u16;
typedef __attribute__((ext_vector_type(8))) __bf16 bf16x8;
typedef __attribute__((ext_vector_type(4))) float f32x4;

#define B_ 4
#define T_ 2048
#define C_ 1024
#define H_ 64
#define NSEG 8

__device__ __forceinline__ u16 f2bf(float f) {
    union { __hip_bfloat16 h; u16 u; } cv;
    cv.h = __float2bfloat16(f);
    return cv.u;
}

__device__ __forceinline__ float bf2f(unsigned v) {
    union { unsigned u; float f; } c; c.u = v << 16; return c.f;
}

__device__ __forceinline__ bf16x8 cvt8r(float4 f0, float4 f1) {
    union { u16 h[8]; bf16x8 v; } ua;
    ua.h[0] = f2bf(f0.x); ua.h[1] = f2bf(f0.y);
    ua.h[2] = f2bf(f0.z); ua.h[3] = f2bf(f0.w);
    ua.h[4] = f2bf(f1.x); ua.h[5] = f2bf(f1.y);
    ua.h[6] = f2bf(f1.z); ua.h[7] = f2bf(f1.w);
    return ua.v;
}

// ---------------- Kernel 0: W fp32 -> bf16 (once) ----------------
__global__ __launch_bounds__(256) void wcvt(
    const float* __restrict__ wq, const float* __restrict__ wk,
    const float* __restrict__ wv, u16* __restrict__ wcat)
{
    int e = (blockIdx.x * 256 + threadIdx.x) * 4;
    int row = e >> 10, col = e & 1023;
    const float* src = (row < 64) ? (wq + (size_t)row * C_)
                     : (row < 128) ? (wk + (size_t)(row - 64) * C_)
                                   : (wv + (size_t)(row - 128) * C_);
    float4 f = *(const float4*)(src + col);
    u16 o[4] = { f2bf(f.x), f2bf(f.y), f2bf(f.z), f2bf(f.w) };
    *(uint2*)(wcat + e) = *(uint2*)o;
}

// ---------------- Kernel 1a: QKV partial GEMM ----------------
// Grid = 256 M-tiles x 4 K-quarters = 1024 blocks, 256 thr (4 waves).
// Wave (kq = w&1, nh = w>>1): 32 rows x 96 cols x K=128 (4 K-steps).
// kq-pair reduced in LDS (1 barrier); kq==0 writes fp32 partial qp[kq4].
__global__ __launch_bounds__(256, 4) void qkv_part(
    const float* __restrict__ x, const u16* __restrict__ wcat,
    float* __restrict__ qp)   // qp[4][8192][192] fp32
{
    __shared__ float red[2][32][98];   // 24.5 KB; max 2-way bank alias (free)

    const int tid  = threadIdx.x;
    const int lane = tid & 63;
    const int w    = tid >> 6;
    const int kq   = w & 1;
    const int nh   = w >> 1;
    const int kq4  = blockIdx.x & 3;
    const int m0   = (blockIdx.x >> 2) * 32;

    const int lr = lane & 15;
    const int g  = lane >> 4;

    const size_t kbase = (size_t)kq4 * 256 + kq * 128 + g * 8;
    const float* xr0 = x + (size_t)(m0 + lr) * C_ + kbase;
    const float* xr1 = x + (size_t)(m0 + 16 + lr) * C_ + kbase;
    const u16*   wb  = wcat + (size_t)(nh * 96 + lr) * C_ + kbase;

    f32x4 acc[2][6] = {};

    #pragma unroll
    for (int kstep = 0; kstep < 4; ++kstep) {
        float4 f00 = *(const float4*)(xr0 + kstep * 32);
        float4 f01 = *(const float4*)(xr0 + kstep * 32 + 4);
        float4 f10 = *(const float4*)(xr1 + kstep * 32);
        float4 f11 = *(const float4*)(xr1 + kstep * 32 + 4);
        bf16x8 a0 = cvt8r(f00, f01);
        bf16x8 a1 = cvt8r(f10, f11);
        #pragma unroll
        for (int j = 0; j < 6; ++j) {
            bf16x8 b = *(const bf16x8*)(wb + (size_t)j * 16 * C_ + kstep * 32);
            acc[0][j] = __builtin_amdgcn_mfma_f32_16x16x32_bf16(a0, b, acc[0][j], 0, 0, 0);
            acc[1][j] = __builtin_amdgcn_mfma_f32_16x16x32_bf16(a1, b, acc[1][j], 0, 0, 0);
        }
    }

    // kq=1 -> LDS; kq=0 adds; then kq=0 stores fp32 partial
    if (kq == 1)
        #pragma unroll
        for (int ms = 0; ms < 2; ++ms)
            #pragma unroll
            for (int j = 0; j < 6; ++j)
                #pragma unroll
                for (int i = 0; i < 4; ++i)
                    red[nh][ms * 16 + g * 4 + i][j * 16 + lr] = acc[ms][j][i];
    __syncthreads();
    if (kq != 0) return;

    #pragma unroll
    for (int ms = 0; ms < 2; ++ms)
        #pragma unroll
        for (int j = 0; j < 6; ++j)
            #pragma unroll
            for (int i = 0; i < 4; ++i)
                acc[ms][j][i] += red[nh][ms * 16 + g * 4 + i][j * 16 + lr];

    float* out = qp + (size_t)kq4 * 8192 * 192;
    #pragma unroll
    for (int ms = 0; ms < 2; ++ms)
        #pragma unroll
        for (int j = 0; j < 6; ++j)
            #pragma unroll
            for (int i = 0; i < 4; ++i)
                out[(size_t)(m0 + ms * 16 + g * 4 + i) * 192 + nh * 96 + j * 16 + lr]
                    = acc[ms][j][i];
}

// ---------------- Kernel 1b: combine 4 K-partials -> bf16 q/k/vT ----------
__global__ __launch_bounds__(256) void qkv_combine(
    const float* __restrict__ qp,
    u16* __restrict__ q, u16* __restrict__ k, u16* __restrict__ vT)
{
    const int idx = blockIdx.x * 256 + threadIdx.x;   // 393216 total
    const int m  = idx / 48;
    const int n0 = (idx % 48) * 4;
    const size_t P = (size_t)8192 * 192;

    const float* p = qp + (size_t)m * 192 + n0;
    float4 s0 = *(const float4*)(p);
    float4 s1 = *(const float4*)(p + P);
    float4 s2 = *(const float4*)(p + 2 * P);
    float4 s3 = *(const float4*)(p + 3 * P);
    float r0 = s0.x + s1.x + s2.x + s3.x;
    float r1 = s0.y + s1.y + s2.y + s3.y;
    float r2 = s0.z + s1.z + s2.z + s3.z;
    float r3 = s0.w + s1.w + s2.w + s3.w;
    u16 o[4] = { f2bf(r0), f2bf(r1), f2bf(r2), f2bf(r3) };

    if (n0 < 64) {
        *(uint2*)(q + (size_t)m * H_ + n0) = *(uint2*)o;
    } else if (n0 < 128) {
        *(uint2*)(k + (size_t)m * H_ + (n0 - 64)) = *(uint2*)o;
    } else {
        int b = m >> 11, t = m & 2047, h = n0 - 128;
        #pragma unroll
        for (int jj = 0; jj < 4; ++jj)
            vT[((size_t)b * H_ + h + jj) * T_ + t] = o[jj];
    }
}

// ---------------- Kernel 2: causal flash attention, KV-split x8 ----------
// 1-wave blocks: no barriers (intra-wave LDS ordering via lgkmcnt); V hoisted.
__global__ __launch_bounds__(64) void attn_part(
    const u16* __restrict__ q, const u16* __restrict__ k,
    const u16* __restrict__ vT, u16* __restrict__ opart,
    float* __restrict__ ml)
{
    __shared__ u16 ps[16 * 72];

    const int lane = threadIdx.x;
    const int bid  = blockIdx.x;
    const int seg  = bid & (NSEG - 1);
    const int tix  = bid >> 3;
    const int b    = tix & 3;
    const int qt   = 127 - (tix >> 2);
    const int q0   = qt * 16;
    const size_t bT = (size_t)b * T_;

    const int lr = lane & 15;
    const int g  = lane >> 4;
    const int lk = g * 8;

    const int nch = (qt >> 2) + 1;
    const int L   = (nch + NSEG - 1) >> 3;
    const int c0  = seg * L;
    const int c1  = min(nch, c0 + L);

    if (c0 >= c1) {
        if (lr == 0)
            #pragma unroll
            for (int i = 0; i < 4; ++i) {
                ml[(size_t)bid * 32 + (g * 4 + i) * 2]     = -1e30f;
                ml[(size_t)bid * 32 + (g * 4 + i) * 2 + 1] = 0.f;
            }
        return;
    }

    bf16x8 aq[2];
    #pragma unroll
    for (int ks = 0; ks < 2; ++ks)
        aq[ks] = *(const bf16x8*)(q + (bT + q0 + lr) * H_ + ks * 32 + lk);

    f32x4 oacc[4] = {};
    float mrow[4], lrow[4];
    #pragma unroll
    for (int i = 0; i < 4; ++i) { mrow[i] = -1e30f; lrow[i] = 0.f; }

    for (int jc = c0; jc < c1; ++jc) {
        const int kv0 = jc << 6;

        bf16x8 bk[8];
        #pragma unroll
        for (int jf = 0; jf < 4; ++jf)
            #pragma unroll
            for (int ks = 0; ks < 2; ++ks)
                bk[jf * 2 + ks] = *(const bf16x8*)(k + (bT + kv0 + jf * 16 + lr) * H_ + ks * 32 + lk);

        f32x4 sacc[4] = {};
        #pragma unroll
        for (int jf = 0; jf < 4; ++jf)
            #pragma unroll
            for (int ks = 0; ks < 2; ++ks)
                sacc[jf] = __builtin_amdgcn_mfma_f32_16x16x32_bf16(aq[ks], bk[jf * 2 + ks], sacc[jf], 0, 0, 0);

        // V fragments issued BEFORE softmax: latency hides under exp/shuffles
        bf16x8 bv[8];
        #pragma unroll
        for (int jf = 0; jf < 4; ++jf)
            #pragma unroll
            for (int ks = 0; ks < 2; ++ks)
                bv[jf * 2 + ks] = *(const bf16x8*)(vT + ((size_t)b * H_ + jf * 16 + lr) * T_ + kv0 + ks * 32 + lk);

        const bool full = (kv0 + 63 <= q0);
        #pragma unroll
        for (int jf = 0; jf < 4; ++jf) {
            int col = kv0 + jf * 16 + lr;
            #pragma unroll
            for (int i = 0; i < 4; ++i) {
                int row = q0 + g * 4 + i;
                float val = sacc[jf][i] * 0.03125f;
                sacc[jf][i] = (full || col <= row) ? val : -1e30f;
            }
        }

        float pnew[4][4];
        #pragma unroll
        for (int i = 0; i < 4; ++i) {
            float mx = fmaxf(fmaxf(sacc[0][i], sacc[1][i]), fmaxf(sacc[2][i], sacc[3][i]));
            mx = fmaxf(mx, __shfl_xor(mx, 1));
            mx = fmaxf(mx, __shfl_xor(mx, 2));
            mx = fmaxf(mx, __shfl_xor(mx, 4));
            mx = fmaxf(mx, __shfl_xor(mx, 8));
            float mnew = fmaxf(mrow[i], mx);
            float corr = __expf(mrow[i] - mnew);
            float rs = 0.f;
            #pragma unroll
            for (int jf = 0; jf < 4; ++jf) {
                float p = __expf(sacc[jf][i] - mnew);
                pnew[jf][i] = p;
                rs += p;
            }
            rs += __shfl_xor(rs, 1);
            rs += __shfl_xor(rs, 2);
            rs += __shfl_xor(rs, 4);
            rs += __shfl_xor(rs, 8);
            lrow[i] = lrow[i] * corr + rs;
            mrow[i] = mnew;
            #pragma unroll
            for (int jf = 0; jf < 4; ++jf) oacc[jf][i] *= corr;
        }

        // P -> LDS (C/D -> A layout) -- single wave, no barrier needed
        #pragma unroll
        for (int jf = 0; jf < 4; ++jf)
            #pragma unroll
            for (int i = 0; i < 4; ++i)
                ps[(g * 4 + i) * 72 + jf * 16 + lr] = f2bf(pnew[jf][i]);

        #pragma unroll
        for (int ks2 = 0; ks2 < 2; ++ks2) {
            bf16x8 ap = *(const bf16x8*)(ps + lr * 72 + ks2 * 32 + lk);
            #pragma unroll
            for (int jf = 0; jf < 4; ++jf)
                oacc[jf] = __builtin_amdgcn_mfma_f32_16x16x32_bf16(ap, bv[jf * 2 + ks2], oacc[jf], 0, 0, 0);
        }
    }

    #pragma unroll
    for (int jf = 0; jf < 4; ++jf)
        #pragma unroll
        for (int i = 0; i < 4; ++i)
            opart[(size_t)bid * 1024 + (g * 4 + i) * 64 + jf * 16 + lr] = f2bf(oacc[jf][i]);
    if (lr == 0)
        #pragma unroll
        for (int i = 0; i < 4; ++i) {
            ml[(size_t)bid * 32 + (g * 4 + i) * 2]     = mrow[i];
            ml[(size_t)bid * 32 + (g * 4 + i) * 2 + 1] = lrow[i];
        }
}

// ---------------- Kernel 3: merge segments (bf16 partials) ----------------
__global__ __launch_bounds__(256) void attn_reduce(
    const u16* __restrict__ opart, const float* __restrict__ ml,
    float* __restrict__ out)
{
    const int t   = blockIdx.x;
    const int row = threadIdx.x >> 4;
    const int p   = threadIdx.x & 15;
    const int b   = t & 3;
    const int qt  = 127 - (t >> 2);

    float m[NSEG], l[NSEG];
    #pragma unroll
    for (int s = 0; s < NSEG; ++s) {
        m[s] = ml[(size_t)(t * NSEG + s) * 32 + row * 2];
        l[s] = ml[(size_t)(t * NSEG + s) * 32 + row * 2 + 1];
    }
    float M = m[0];
    #pragma unroll
    for (int s = 1; s < NSEG; ++s) M = fmaxf(M, m[s]);

    float a0 = 0.f, a1 = 0.f, a2 = 0.f, a3 = 0.f, Lsum = 0.f;
    #pragma unroll
    for (int s = 0; s < NSEG; ++s) {
        float wgt = __expf(m[s] - M);
        Lsum += l[s] * wgt;
        uint2 o = *(const uint2*)(opart + (size_t)(t * NSEG + s) * 1024 + row * 64 + p * 4);
        a0 += wgt * bf2f(o.x & 0xffffu);
        a1 += wgt * bf2f(o.x >> 16);
        a2 += wgt * bf2f(o.y & 0xffffu);
        a3 += wgt * bf2f(o.y >> 16);
    }
    float inv = 1.f / Lsum;
    float4 r; r.x = a0 * inv; r.y = a1 * inv; r.z = a2 * inv; r.w = a3 * inv;
    *(float4*)(out + ((size_t)b * T_ + qt * 16 + row) * H_ + p * 4) = r;
}

extern "C" void kernel_launch(void* const* d_in, const int* in_sizes, int n_in,
                              void* d_out, int out_size, void* d_ws, size_t ws_size,
                              hipStream_t stream) {
    const float* x  = (const float*)d_in[0];
    const float* wq = (const float*)d_in[1];
    const float* wk = (const float*)d_in[2];
    const float* wv = (const float*)d_in[3];

    u16* qws  = (u16*)d_ws;                          // 1 MB
    u16* kws  = qws + (size_t)B_ * T_ * H_;          // 1 MB
    u16* vTws = kws + (size_t)B_ * T_ * H_;          // 1 MB
    u16* wcat = vTws + (size_t)B_ * T_ * H_;         // 384 KB
    u16* opart = wcat + (size_t)192 * C_;            // 8.4 MB
    float* mlbuf = (float*)(opart + (size_t)4096 * 1024);  // 512 KB
    float* qp = mlbuf + (size_t)4096 * 32;           // 4*8192*192 f32 = 25.2 MB

    wcvt<<<192, 256, 0, stream>>>(wq, wk, wv, wcat);
    qkv_part<<<1024, 256, 0, stream>>>(x, wcat, qp);
    qkv_combine<<<1536, 256, 0, stream>>>(qp, qws, kws, vTws);
    attn_part<<<4096, 64, 0, stream>>>(qws, kws, vTws, opart, mlbuf);
    attn_reduce<<<512, 256, 0, stream>>>(opart, mlbuf, (float*)d_out);
}

// Round 12
// 65.828 us; speedup vs baseline: 1.0404x; 1.0083x over previous
//
#include <hip/hip_runtime.h>
#include <hip/hip_bf16.h>

typedef unsigned short u16;
typedef __attribute__((ext_vector_type(8))) __bf16 bf16x8;
typedef __attribute__((ext_vector_type(4))) float f32x4;

#define B_ 4
#define T_ 2048
#define C_ 1024
#define H_ 64
#define NSEG 8

__device__ __forceinline__ u16 f2bf(float f) {
    union { __hip_bfloat16 h; u16 u; } cv;
    cv.h = __float2bfloat16(f);
    return cv.u;
}

__device__ __forceinline__ float bf2f(unsigned v) {
    union { unsigned u; float f; } c; c.u = v << 16; return c.f;
}

__device__ __forceinline__ bf16x8 cvt8r(float4 f0, float4 f1) {
    union { u16 h[8]; bf16x8 v; } ua;
    ua.h[0] = f2bf(f0.x); ua.h[1] = f2bf(f0.y);
    ua.h[2] = f2bf(f0.z); ua.h[3] = f2bf(f0.w);
    ua.h[4] = f2bf(f1.x); ua.h[5] = f2bf(f1.y);
    ua.h[6] = f2bf(f1.z); ua.h[7] = f2bf(f1.w);
    return ua.v;
}

// ---------------- Kernel 0: W fp32 -> bf16 (once) ----------------
__global__ __launch_bounds__(256) void wcvt(
    const float* __restrict__ wq, const float* __restrict__ wk,
    const float* __restrict__ wv, u16* __restrict__ wcat)
{
    int e = (blockIdx.x * 256 + threadIdx.x) * 4;
    int row = e >> 10, col = e & 1023;
    const float* src = (row < 64) ? (wq + (size_t)row * C_)
                     : (row < 128) ? (wk + (size_t)(row - 64) * C_)
                                   : (wv + (size_t)(row - 128) * C_);
    float4 f = *(const float4*)(src + col);
    u16 o[4] = { f2bf(f.x), f2bf(f.y), f2bf(f.z), f2bf(f.w) };
    *(uint2*)(wcat + e) = *(uint2*)o;
}

// ---------------- Kernel 1: QKV projection, N-split waves, LDS-staged x ---
// Block = 32 rows x 192 cols, 8 waves = (ms 0..1) x (nh 0..3); wave owns
// 16x48 output (acc = 3 f32x4). K-loop: 16 chunks of 64. x double-buffered
// in LDS (8KB/buf) with XOR swizzle (row&7)<<4; W direct 16B loads from L2.
__global__ __launch_bounds__(512) void qkv(
    const float* __restrict__ x, const u16* __restrict__ wcat,
    u16* __restrict__ q, u16* __restrict__ k, u16* __restrict__ vT)
{
    __shared__ __align__(16) char xls[2][8192];   // [buf][row*256 + swizzled byte]

    const int tid = threadIdx.x;
    const int ln  = tid & 63;
    const int wv  = tid >> 6;
    const int m0  = blockIdx.x * 32;

    const int lr = ln & 15;
    const int g  = ln >> 4;
    const int ms = wv >> 2;      // 0..1  (16-row half)
    const int nh = wv & 3;       // 0..3  (48-col quarter)

    // ---- staging geometry (per thread: one 16B piece of the 8KB x tile) ----
    const int srow = tid >> 4;                     // 0..31
    const int swin = (tid & 15) * 16;              // 0..240, byte in 256B row
    const int sws  = swin ^ ((srow & 7) << 4);     // swizzled LDS byte in row
    const char* xsrc = (const char*)(x + (size_t)(m0 + srow) * C_) + swin;

    // ---- A-read geometry (swizzled) ----
    const int r   = ms * 16 + lr;                  // 0..31
    const int rsw = (r & 7) << 4;

    const u16* wb = wcat + (size_t)(nh * 48 + lr) * C_ + g * 8;

    f32x4 acc[3] = {};

    // prologue: stage chunk 0 into buf 0
    {
        float4 p0 = *(const float4*)(xsrc);
        *(float4*)(&xls[0][srow * 256 + sws]) = p0;
    }

    for (int kc = 0; kc < 16; ++kc) {
        __syncthreads();                           // buf[kc&1] ready
        const char* rb = &xls[kc & 1][0];

        // prefetch next chunk (global, issued early; HBM hides under compute)
        float4 pre = {};
        if (kc < 15)
            pre = *(const float4*)(xsrc + (kc + 1) * 256);

        // A fragments from LDS (swizzled reads, conflict-free)
        bf16x8 a[2];
        #pragma unroll
        for (int ks = 0; ks < 2; ++ks) {
            const int w0 = ks * 128 + g * 32;
            float4 fa = *(const float4*)(rb + r * 256 + (w0 ^ rsw));
            float4 fb = *(const float4*)(rb + r * 256 + ((w0 + 16) ^ rsw));
            a[ks] = cvt8r(fa, fb);
        }

        // B fragments direct from L2 + MFMA (6 per chunk)
        #pragma unroll
        for (int j = 0; j < 3; ++j) {
            #pragma unroll
            for (int ks = 0; ks < 2; ++ks) {
                bf16x8 b = *(const bf16x8*)(wb + (size_t)j * 16 * C_ + kc * 64 + ks * 32);
                acc[j] = __builtin_amdgcn_mfma_f32_16x16x32_bf16(a[ks], b, acc[j], 0, 0, 0);
            }
        }

        // late write of the prefetched chunk into the other buffer
        if (kc < 15)
            *(float4*)(&xls[(kc + 1) & 1][srow * 256 + sws]) = pre;
    }

    // epilogue: C/D layout col=lane&15, row=(lane>>4)*4+i
    #pragma unroll
    for (int j = 0; j < 3; ++j) {
        int n = nh * 48 + j * 16 + lr;
        #pragma unroll
        for (int i = 0; i < 4; ++i) {
            int m = m0 + ms * 16 + g * 4 + i;
            u16 val = f2bf(acc[j][i]);
            if (n < 64) {
                q[(size_t)m * H_ + n] = val;
            } else if (n < 128) {
                k[(size_t)m * H_ + (n - 64)] = val;
            } else {
                int b = m >> 11, t = m & 2047;
                vT[((size_t)b * H_ + (n - 128)) * T_ + t] = val;
            }
        }
    }
}

// ---------------- Kernel 2: causal flash attention, KV-split x8 ----------
// 1-wave blocks: no barriers (intra-wave LDS ordering via lgkmcnt); V hoisted.
__global__ __launch_bounds__(64) void attn_part(
    const u16* __restrict__ q, const u16* __restrict__ k,
    const u16* __restrict__ vT, u16* __restrict__ opart,
    float* __restrict__ ml)
{
    __shared__ u16 ps[16 * 72];

    const int lane = threadIdx.x;
    const int bid  = blockIdx.x;
    const int seg  = bid & (NSEG - 1);
    const int tix  = bid >> 3;
    const int b    = tix & 3;
    const int qt   = 127 - (tix >> 2);
    const int q0   = qt * 16;
    const size_t bT = (size_t)b * T_;

    const int lr = lane & 15;
    const int g  = lane >> 4;
    const int lk = g * 8;

    const int nch = (qt >> 2) + 1;
    const int L   = (nch + NSEG - 1) >> 3;
    const int c0  = seg * L;
    const int c1  = min(nch, c0 + L);

    if (c0 >= c1) {
        if (lr == 0)
            #pragma unroll
            for (int i = 0; i < 4; ++i) {
                ml[(size_t)bid * 32 + (g * 4 + i) * 2]     = -1e30f;
                ml[(size_t)bid * 32 + (g * 4 + i) * 2 + 1] = 0.f;
            }
        return;
    }

    bf16x8 aq[2];
    #pragma unroll
    for (int ks = 0; ks < 2; ++ks)
        aq[ks] = *(const bf16x8*)(q + (bT + q0 + lr) * H_ + ks * 32 + lk);

    f32x4 oacc[4] = {};
    float mrow[4], lrow[4];
    #pragma unroll
    for (int i = 0; i < 4; ++i) { mrow[i] = -1e30f; lrow[i] = 0.f; }

    for (int jc = c0; jc < c1; ++jc) {
        const int kv0 = jc << 6;

        bf16x8 bk[8];
        #pragma unroll
        for (int jf = 0; jf < 4; ++jf)
            #pragma unroll
            for (int ks = 0; ks < 2; ++ks)
                bk[jf * 2 + ks] = *(const bf16x8*)(k + (bT + kv0 + jf * 16 + lr) * H_ + ks * 32 + lk);

        f32x4 sacc[4] = {};
        #pragma unroll
        for (int jf = 0; jf < 4; ++jf)
            #pragma unroll
            for (int ks = 0; ks < 2; ++ks)
                sacc[jf] = __builtin_amdgcn_mfma_f32_16x16x32_bf16(aq[ks], bk[jf * 2 + ks], sacc[jf], 0, 0, 0);

        // V fragments issued BEFORE softmax: latency hides under exp/shuffles
        bf16x8 bv[8];
        #pragma unroll
        for (int jf = 0; jf < 4; ++jf)
            #pragma unroll
            for (int ks = 0; ks < 2; ++ks)
                bv[jf * 2 + ks] = *(const bf16x8*)(vT + ((size_t)b * H_ + jf * 16 + lr) * T_ + kv0 + ks * 32 + lk);

        const bool full = (kv0 + 63 <= q0);
        #pragma unroll
        for (int jf = 0; jf < 4; ++jf) {
            int col = kv0 + jf * 16 + lr;
            #pragma unroll
            for (int i = 0; i < 4; ++i) {
                int row = q0 + g * 4 + i;
                float val = sacc[jf][i] * 0.03125f;
                sacc[jf][i] = (full || col <= row) ? val : -1e30f;
            }
        }

        float pnew[4][4];
        #pragma unroll
        for (int i = 0; i < 4; ++i) {
            float mx = fmaxf(fmaxf(sacc[0][i], sacc[1][i]), fmaxf(sacc[2][i], sacc[3][i]));
            mx = fmaxf(mx, __shfl_xor(mx, 1));
            mx = fmaxf(mx, __shfl_xor(mx, 2));
            mx = fmaxf(mx, __shfl_xor(mx, 4));
            mx = fmaxf(mx, __shfl_xor(mx, 8));
            float mnew = fmaxf(mrow[i], mx);
            float corr = __expf(mrow[i] - mnew);
            float rs = 0.f;
            #pragma unroll
            for (int jf = 0; jf < 4; ++jf) {
                float p = __expf(sacc[jf][i] - mnew);
                pnew[jf][i] = p;
                rs += p;
            }
            rs += __shfl_xor(rs, 1);
            rs += __shfl_xor(rs, 2);
            rs += __shfl_xor(rs, 4);
            rs += __shfl_xor(rs, 8);
            lrow[i] = lrow[i] * corr + rs;
            mrow[i] = mnew;
            #pragma unroll
            for (int jf = 0; jf < 4; ++jf) oacc[jf][i] *= corr;
        }

        // P -> LDS (C/D -> A layout) -- single wave, no barrier needed
        #pragma unroll
        for (int jf = 0; jf < 4; ++jf)
            #pragma unroll
            for (int i = 0; i < 4; ++i)
                ps[(g * 4 + i) * 72 + jf * 16 + lr] = f2bf(pnew[jf][i]);

        #pragma unroll
        for (int ks2 = 0; ks2 < 2; ++ks2) {
            bf16x8 ap = *(const bf16x8*)(ps + lr * 72 + ks2 * 32 + lk);
            #pragma unroll
            for (int jf = 0; jf < 4; ++jf)
                oacc[jf] = __builtin_amdgcn_mfma_f32_16x16x32_bf16(ap, bv[jf * 2 + ks2], oacc[jf], 0, 0, 0);
        }
    }

    #pragma unroll
    for (int jf = 0; jf < 4; ++jf)
        #pragma unroll
        for (int i = 0; i < 4; ++i)
            opart[(size_t)bid * 1024 + (g * 4 + i) * 64 + jf * 16 + lr] = f2bf(oacc[jf][i]);
    if (lr == 0)
        #pragma unroll
        for (int i = 0; i < 4; ++i) {
            ml[(size_t)bid * 32 + (g * 4 + i) * 2]     = mrow[i];
            ml[(size_t)bid * 32 + (g * 4 + i) * 2 + 1] = lrow[i];
        }
}

// ---------------- Kernel 3: merge segments (bf16 partials) ----------------
__global__ __launch_bounds__(256) void attn_reduce(
    const u16* __restrict__ opart, const float* __restrict__ ml,
    float* __restrict__ out)
{
    const int t   = blockIdx.x;
    const int row = threadIdx.x >> 4;
    const int p   = threadIdx.x & 15;
    const int b   = t & 3;
    const int qt  = 127 - (t >> 2);

    float m[NSEG], l[NSEG];
    #pragma unroll
    for (int s = 0; s < NSEG; ++s) {
        m[s] = ml[(size_t)(t * NSEG + s) * 32 + row * 2];
        l[s] = ml[(size_t)(t * NSEG + s) * 32 + row * 2 + 1];
    }
    float M = m[0];
    #pragma unroll
    for (int s = 1; s < NSEG; ++s) M = fmaxf(M, m[s]);

    float a0 = 0.f, a1 = 0.f, a2 = 0.f, a3 = 0.f, Lsum = 0.f;
    #pragma unroll
    for (int s = 0; s < NSEG; ++s) {
        float wgt = __expf(m[s] - M);
        Lsum += l[s] * wgt;
        uint2 o = *(const uint2*)(opart + (size_t)(t * NSEG + s) * 1024 + row * 64 + p * 4);
        a0 += wgt * bf2f(o.x & 0xffffu);
        a1 += wgt * bf2f(o.x >> 16);
        a2 += wgt * bf2f(o.y & 0xffffu);
        a3 += wgt * bf2f(o.y >> 16);
    }
    float inv = 1.f / Lsum;
    float4 r; r.x = a0 * inv; r.y = a1 * inv; r.z = a2 * inv; r.w = a3 * inv;
    *(float4*)(out + ((size_t)b * T_ + qt * 16 + row) * H_ + p * 4) = r;
}

extern "C" void kernel_launch(void* const* d_in, const int* in_sizes, int n_in,
                              void* d_out, int out_size, void* d_ws, size_t ws_size,
                              hipStream_t stream) {
    const float* x  = (const float*)d_in[0];
    const float* wq = (const float*)d_in[1];
    const float* wk = (const float*)d_in[2];
    const float* wv = (const float*)d_in[3];

    u16* qws  = (u16*)d_ws;                          // 1 MB
    u16* kws  = qws + (size_t)B_ * T_ * H_;          // 1 MB
    u16* vTws = kws + (size_t)B_ * T_ * H_;          // 1 MB
    u16* wcat = vTws + (size_t)B_ * T_ * H_;         // 384 KB
    u16* opart = wcat + (size_t)192 * C_;            // 8.4 MB
    float* mlbuf = (float*)(opart + (size_t)4096 * 1024);  // 512 KB

    wcvt<<<192, 256, 0, stream>>>(wq, wk, wv, wcat);
    qkv<<<256, 512, 0, stream>>>(x, wcat, qws, kws, vTws);
    attn_part<<<4096, 64, 0, stream>>>(qws, kws, vTws, opart, mlbuf);
    attn_reduce<<<512, 256, 0, stream>>>(opart, mlbuf, (float*)d_out);
}

// Round 13
// 58.014 us; speedup vs baseline: 1.1805x; 1.1347x over previous
//
#include <hip/hip_runtime.h>
#include <hip/hip_bf16.h>

typedef unsigned short u16;
typedef __attribute__((ext_vector_type(8))) __bf16 bf16x8;
typedef __attribute__((ext_vector_type(4))) float f32x4;

#define B_ 4
#define T_ 2048
#define C_ 1024
#define H_ 64
#define NSEG 8

__device__ __forceinline__ u16 f2bf(float f) {
    union { __hip_bfloat16 h; u16 u; } cv;
    cv.h = __float2bfloat16(f);
    return cv.u;
}

__device__ __forceinline__ float bf2f(unsigned v) {
    union { unsigned u; float f; } c; c.u = v << 16; return c.f;
}

__device__ __forceinline__ bf16x8 cvt8r(float4 f0, float4 f1) {
    union { u16 h[8]; bf16x8 v; } ua;
    ua.h[0] = f2bf(f0.x); ua.h[1] = f2bf(f0.y);
    ua.h[2] = f2bf(f0.z); ua.h[3] = f2bf(f0.w);
    ua.h[4] = f2bf(f1.x); ua.h[5] = f2bf(f1.y);
    ua.h[6] = f2bf(f1.z); ua.h[7] = f2bf(f1.w);
    return ua.v;
}

// async global -> LDS, 16B per lane; LDS dest = uniform base + lane*16
__device__ __forceinline__ void gll16(const void* g, void* l) {
    __builtin_amdgcn_global_load_lds(
        (const __attribute__((address_space(1))) void*)g,
        (__attribute__((address_space(3))) void*)l, 16, 0, 0);
}

// ---------------- Kernel 0: W fp32 -> bf16 (once) ----------------
__global__ __launch_bounds__(256) void wcvt(
    const float* __restrict__ wq, const float* __restrict__ wk,
    const float* __restrict__ wv, u16* __restrict__ wcat)
{
    int e = (blockIdx.x * 256 + threadIdx.x) * 4;
    int row = e >> 10, col = e & 1023;
    const float* src = (row < 64) ? (wq + (size_t)row * C_)
                     : (row < 128) ? (wk + (size_t)(row - 64) * C_)
                                   : (wv + (size_t)(row - 128) * C_);
    float4 f = *(const float4*)(src + col);
    u16 o[4] = { f2bf(f.x), f2bf(f.y), f2bf(f.z), f2bf(f.w) };
    *(uint2*)(wcat + e) = *(uint2*)o;
}

// ---------------- Kernel 1: QKV projection (m97-style staged GEMM) -------
// 256 blocks x 256 thr (4 waves). Tile 32 rows x 192 cols, K-chunks of 64.
// Wave w = (ms = w>>1) x (nh = w&1): 16 rows x 96 cols, acc[6].
// Both operands staged via global_load_lds (16B/lane, double-buffered):
//   x  region:  8 KB/buf = 8 segs of 1KB (4 rows x 256B fp32)
//   W  region: 24 KB/buf = 24 segs of 1KB (8 rows x 128B bf16)
// XOR swizzle (rule #21): pre-swizzled GLOBAL source + linear LDS dest +
// swizzled ds_read on the read side. chunk16 ^= (row & 7).
__global__ __launch_bounds__(256) void qkv(
    const float* __restrict__ x, const u16* __restrict__ wcat,
    u16* __restrict__ q, u16* __restrict__ k, u16* __restrict__ vT)
{
    __shared__ __align__(16) char lds[2][32768];   // [buf][x 0..8K | W 8K..32K]

    const int tid = threadIdx.x;
    const int ln  = tid & 63;
    const int w   = tid >> 6;
    const int m0  = blockIdx.x * 32;

    const int lr = ln & 15;
    const int g  = ln >> 4;
    const int ms = w >> 1;
    const int nh = w & 1;

    f32x4 acc[6] = {};

    // ---- staging: wave w issues 2 x-segs + 6 W-segs per chunk ----
    // (addresses precomputed as row/chunk; kc advances by 64 elems)
    const int xs0  = w * 2;                        // x seg base (2 segs)
    const int xrow0 = xs0 * 4 + (ln >> 4);         // global x row (local 0..31)
    const int xc0   = (ln & 15) ^ (xrow0 & 7);     // pre-swizzled 16B chunk
    const int xrow1 = (xs0 + 1) * 4 + (ln >> 4);
    const int xc1   = (ln & 15) ^ (xrow1 & 7);

    const int wseg0 = w * 6;                       // W seg base (6 segs)
    const int wlr   = ln >> 3;                     // 0..7 row-in-seg
    const int wc    = (ln & 7) ^ wlr;              // pre-swizzled 16B chunk

#define STAGE(BUF, KC)                                                         \
    do {                                                                       \
        gll16(x + (size_t)(m0 + xrow0) * C_ + (KC) * 64 + xc0 * 4,             \
              &lds[BUF][xs0 * 1024]);                                          \
        gll16(x + (size_t)(m0 + xrow1) * C_ + (KC) * 64 + xc1 * 4,             \
              &lds[BUF][(xs0 + 1) * 1024]);                                    \
        _Pragma("unroll")                                                      \
        for (int i_ = 0; i_ < 6; ++i_) {                                       \
            int s_ = wseg0 + i_;                                               \
            gll16(wcat + (size_t)(s_ * 8 + wlr) * C_ + (KC) * 64 + wc * 8,     \
                  &lds[BUF][8192 + s_ * 1024]);                                \
        }                                                                      \
    } while (0)

    STAGE(0, 0);
    __syncthreads();

    const int ra  = ms * 16 + lr;                  // A row 0..31
    const int rsw = ra & 7;

    for (int kc = 0; kc < 16; ++kc) {
        const int buf = kc & 1;
        if (kc < 15) STAGE(buf ^ 1, kc + 1);       // issue next stage early

        const char* rb = &lds[buf][0];
        const char* wb = &lds[buf][8192];

        // A fragments: fp32 from swizzled LDS -> bf16
        bf16x8 a[2];
        #pragma unroll
        for (int ks = 0; ks < 2; ++ks) {
            int c0 = ks * 8 + g * 2;
            float4 fa = *(const float4*)(rb + ra * 256 + ((c0     ^ rsw) << 4));
            float4 fb = *(const float4*)(rb + ra * 256 + (((c0+1) ^ rsw) << 4));
            a[ks] = cvt8r(fa, fb);
        }

        // B fragments from swizzled LDS + MFMA (12 per wave per chunk)
        #pragma unroll
        for (int j = 0; j < 6; ++j) {
            int rr = nh * 96 + j * 16 + lr;
            #pragma unroll
            for (int ks = 0; ks < 2; ++ks) {
                int c = (ks * 4 + g) ^ (lr & 7);
                bf16x8 b = *(const bf16x8*)(wb + rr * 128 + c * 16);
                acc[j] = __builtin_amdgcn_mfma_f32_16x16x32_bf16(a[ks], b, acc[j], 0, 0, 0);
            }
        }

        __syncthreads();   // drains stage (vmcnt) + protects buf reuse
    }
#undef STAGE

    // epilogue: C/D layout col=lane&15, row=(lane>>4)*4+i
    #pragma unroll
    for (int j = 0; j < 6; ++j) {
        int n = nh * 96 + j * 16 + lr;
        #pragma unroll
        for (int i = 0; i < 4; ++i) {
            int m = m0 + ms * 16 + g * 4 + i;
            u16 val = f2bf(acc[j][i]);
            if (n < 64) {
                q[(size_t)m * H_ + n] = val;
            } else if (n < 128) {
                k[(size_t)m * H_ + (n - 64)] = val;
            } else {
                int b = m >> 11, t = m & 2047;
                vT[((size_t)b * H_ + (n - 128)) * T_ + t] = val;
            }
        }
    }
}

// ---------------- Kernel 2: causal flash attention, KV-split x8 ----------
// 1-wave blocks: no barriers (intra-wave LDS ordering via lgkmcnt); V hoisted.
__global__ __launch_bounds__(64) void attn_part(
    const u16* __restrict__ q, const u16* __restrict__ k,
    const u16* __restrict__ vT, u16* __restrict__ opart,
    float* __restrict__ ml)
{
    __shared__ u16 ps[16 * 72];

    const int lane = threadIdx.x;
    const int bid  = blockIdx.x;
    const int seg  = bid & (NSEG - 1);
    const int tix  = bid >> 3;
    const int b    = tix & 3;
    const int qt   = 127 - (tix >> 2);
    const int q0   = qt * 16;
    const size_t bT = (size_t)b * T_;

    const int lr = lane & 15;
    const int g  = lane >> 4;
    const int lk = g * 8;

    const int nch = (qt >> 2) + 1;
    const int L   = (nch + NSEG - 1) >> 3;
    const int c0  = seg * L;
    const int c1  = min(nch, c0 + L);

    if (c0 >= c1) {
        if (lr == 0)
            #pragma unroll
            for (int i = 0; i < 4; ++i) {
                ml[(size_t)bid * 32 + (g * 4 + i) * 2]     = -1e30f;
                ml[(size_t)bid * 32 + (g * 4 + i) * 2 + 1] = 0.f;
            }
        return;
    }

    bf16x8 aq[2];
    #pragma unroll
    for (int ks = 0; ks < 2; ++ks)
        aq[ks] = *(const bf16x8*)(q + (bT + q0 + lr) * H_ + ks * 32 + lk);

    f32x4 oacc[4] = {};
    float mrow[4], lrow[4];
    #pragma unroll
    for (int i = 0; i < 4; ++i) { mrow[i] = -1e30f; lrow[i] = 0.f; }

    for (int jc = c0; jc < c1; ++jc) {
        const int kv0 = jc << 6;

        bf16x8 bk[8];
        #pragma unroll
        for (int jf = 0; jf < 4; ++jf)
            #pragma unroll
            for (int ks = 0; ks < 2; ++ks)
                bk[jf * 2 + ks] = *(const bf16x8*)(k + (bT + kv0 + jf * 16 + lr) * H_ + ks * 32 + lk);

        f32x4 sacc[4] = {};
        #pragma unroll
        for (int jf = 0; jf < 4; ++jf)
            #pragma unroll
            for (int ks = 0; ks < 2; ++ks)
                sacc[jf] = __builtin_amdgcn_mfma_f32_16x16x32_bf16(aq[ks], bk[jf * 2 + ks], sacc[jf], 0, 0, 0);

        // V fragments issued BEFORE softmax: latency hides under exp/shuffles
        bf16x8 bv[8];
        #pragma unroll
        for (int jf = 0; jf < 4; ++jf)
            #pragma unroll
            for (int ks = 0; ks < 2; ++ks)
                bv[jf * 2 + ks] = *(const bf16x8*)(vT + ((size_t)b * H_ + jf * 16 + lr) * T_ + kv0 + ks * 32 + lk);

        const bool full = (kv0 + 63 <= q0);
        #pragma unroll
        for (int jf = 0; jf < 4; ++jf) {
            int col = kv0 + jf * 16 + lr;
            #pragma unroll
            for (int i = 0; i < 4; ++i) {
                int row = q0 + g * 4 + i;
                float val = sacc[jf][i] * 0.03125f;
                sacc[jf][i] = (full || col <= row) ? val : -1e30f;
            }
        }

        float pnew[4][4];
        #pragma unroll
        for (int i = 0; i < 4; ++i) {
            float mx = fmaxf(fmaxf(sacc[0][i], sacc[1][i]), fmaxf(sacc[2][i], sacc[3][i]));
            mx = fmaxf(mx, __shfl_xor(mx, 1));
            mx = fmaxf(mx, __shfl_xor(mx, 2));
            mx = fmaxf(mx, __shfl_xor(mx, 4));
            mx = fmaxf(mx, __shfl_xor(mx, 8));
            float mnew = fmaxf(mrow[i], mx);
            float corr = __expf(mrow[i] - mnew);
            float rs = 0.f;
            #pragma unroll
            for (int jf = 0; jf < 4; ++jf) {
                float p = __expf(sacc[jf][i] - mnew);
                pnew[jf][i] = p;
                rs += p;
            }
            rs += __shfl_xor(rs, 1);
            rs += __shfl_xor(rs, 2);
            rs += __shfl_xor(rs, 4);
            rs += __shfl_xor(rs, 8);
            lrow[i] = lrow[i] * corr + rs;
            mrow[i] = mnew;
            #pragma unroll
            for (int jf = 0; jf < 4; ++jf) oacc[jf][i] *= corr;
        }

        // P -> LDS (C/D -> A layout) -- single wave, no barrier needed
        #pragma unroll
        for (int jf = 0; jf < 4; ++jf)
            #pragma unroll
            for (int i = 0; i < 4; ++i)
                ps[(g * 4 + i) * 72 + jf * 16 + lr] = f2bf(pnew[jf][i]);

        #pragma unroll
        for (int ks2 = 0; ks2 < 2; ++ks2) {
            bf16x8 ap = *(const bf16x8*)(ps + lr * 72 + ks2 * 32 + lk);
            #pragma unroll
            for (int jf = 0; jf < 4; ++jf)
                oacc[jf] = __builtin_amdgcn_mfma_f32_16x16x32_bf16(ap, bv[jf * 2 + ks2], oacc[jf], 0, 0, 0);
        }
    }

    #pragma unroll
    for (int jf = 0; jf < 4; ++jf)
        #pragma unroll
        for (int i = 0; i < 4; ++i)
            opart[(size_t)bid * 1024 + (g * 4 + i) * 64 + jf * 16 + lr] = f2bf(oacc[jf][i]);
    if (lr == 0)
        #pragma unroll
        for (int i = 0; i < 4; ++i) {
            ml[(size_t)bid * 32 + (g * 4 + i) * 2]     = mrow[i];
            ml[(size_t)bid * 32 + (g * 4 + i) * 2 + 1] = lrow[i];
        }
}

// ---------------- Kernel 3: merge segments (bf16 partials) ----------------
__global__ __launch_bounds__(256) void attn_reduce(
    const u16* __restrict__ opart, const float* __restrict__ ml,
    float* __restrict__ out)
{
    const int t   = blockIdx.x;
    const int row = threadIdx.x >> 4;
    const int p   = threadIdx.x & 15;
    const int b   = t & 3;
    const int qt  = 127 - (t >> 2);

    float m[NSEG], l[NSEG];
    #pragma unroll
    for (int s = 0; s < NSEG; ++s) {
        m[s] = ml[(size_t)(t * NSEG + s) * 32 + row * 2];
        l[s] = ml[(size_t)(t * NSEG + s) * 32 + row * 2 + 1];
    }
    float M = m[0];
    #pragma unroll
    for (int s = 1; s < NSEG; ++s) M = fmaxf(M, m[s]);

    float a0 = 0.f, a1 = 0.f, a2 = 0.f, a3 = 0.f, Lsum = 0.f;
    #pragma unroll
    for (int s = 0; s < NSEG; ++s) {
        float wgt = __expf(m[s] - M);
        Lsum += l[s] * wgt;
        uint2 o = *(const uint2*)(opart + (size_t)(t * NSEG + s) * 1024 + row * 64 + p * 4);
        a0 += wgt * bf2f(o.x & 0xffffu);
        a1 += wgt * bf2f(o.x >> 16);
        a2 += wgt * bf2f(o.y & 0xffffu);
        a3 += wgt * bf2f(o.y >> 16);
    }
    float inv = 1.f / Lsum;
    float4 r; r.x = a0 * inv; r.y = a1 * inv; r.z = a2 * inv; r.w = a3 * inv;
    *(float4*)(out + ((size_t)b * T_ + qt * 16 + row) * H_ + p * 4) = r;
}

extern "C" void kernel_launch(void* const* d_in, const int* in_sizes, int n_in,
                              void* d_out, int out_size, void* d_ws, size_t ws_size,
                              hipStream_t stream) {
    const float* x  = (const float*)d_in[0];
    const float* wq = (const float*)d_in[1];
    const float* wk = (const float*)d_in[2];
    const float* wv = (const float*)d_in[3];

    u16* qws  = (u16*)d_ws;                          // 1 MB
    u16* kws  = qws + (size_t)B_ * T_ * H_;          // 1 MB
    u16* vTws = kws + (size_t)B_ * T_ * H_;          // 1 MB
    u16* wcat = vTws + (size_t)B_ * T_ * H_;         // 384 KB
    u16* opart = wcat + (size_t)192 * C_;            // 8.4 MB
    float* mlbuf = (float*)(opart + (size_t)4096 * 1024);  // 512 KB

    wcvt<<<192, 256, 0, stream>>>(wq, wk, wv, wcat);
    qkv<<<256, 256, 0, stream>>>(x, wcat, qws, kws, vTws);
    attn_part<<<4096, 64, 0, stream>>>(qws, kws, vTws, opart, mlbuf);
    attn_reduce<<<512, 256, 0, stream>>>(opart, mlbuf, (float*)d_out);
}